// Round 1
// 134.712 us; speedup vs baseline: 1.0058x; 1.0058x over previous
//
#include <hip/hip_runtime.h>
#include <cmath>

#define P 5
#define LBV 0.0f
#define UBV 0.5f
#define RFV 1.03f
#define ALPHA 0.1f
#define OMEGA 0.05f
#define BETA 0.05f
#define MU 0.01f
#define NTHR 256

// async global->LDS, 16B per lane. LDS dest must be wave-uniform base + lane*16,
// which a linear copy (index = i*NTHR + tid) satisfies exactly.
#define GLOAD_LDS16(gp, lp)                                                      \
    __builtin_amdgcn_global_load_lds(                                            \
        (const __attribute__((address_space(1))) void*)(gp),                     \
        (__attribute__((address_space(3))) void*)(lp), 16, 0, 0)

// tanh via HW v_exp_f32 + v_rcp_f32. For |x| large, exp(-2|x|)->0 => r->1.
__device__ __forceinline__ float fast_tanh(float x) {
    float ax = fabsf(x);
    float t  = __expf(-2.0f * ax);                       // v_mul + v_exp_f32
    float r  = (1.0f - t) * __builtin_amdgcn_rcpf(1.0f + t);
    return copysignf(r, x);                              // v_bfi
}

// One thread per sample. Only layer k=3 contributes to the output (the
// reference loop re-consumes the ORIGINAL x1/x2 each iteration and only the
// last iteration's wealth/curr_cov survive).
__global__ __launch_bounds__(NTHR) void portfolio_kernel(
    const float* __restrict__ x1,
    const float* __restrict__ x2,
    const float* __restrict__ eps,
    const float* __restrict__ W,
    float* __restrict__ out, int B)
{
    __shared__ float  sW[3 * P * P];                 // 75 floats
    __shared__ float4 sX2[(NTHR * P * P) / 4];       // 1600 float4 = 25.6 KB
    __shared__ float4 sE[(NTHR * P) / 4];            // 320 float4 = 5 KB

    const int tid = threadIdx.x;
    const int b0  = blockIdx.x * NTHR;

    // x1 early: overlap its latency with the LDS staging.
    float x1v = x1[b0 + tid];

    if (tid < 3 * P * P) sW[tid] = W[3 * 3 * P * P + tid];

    // ---- async 16B staging: x2 (1600 float4/block = 6.25/thread) ----
    const float4* g4 = (const float4*)(x2 + (size_t)b0 * (P * P));
    #pragma unroll
    for (int i = 0; i < 6; ++i)
        GLOAD_LDS16(g4 + i * NTHR + tid, &sX2[i * NTHR + tid]);
    if (tid < 64)
        GLOAD_LDS16(g4 + 6 * NTHR + tid, &sX2[6 * NTHR + tid]);

    // ---- async 16B staging: eps[3] (320 float4/block = 1.25/thread) ----
    const float4* ge4 = (const float4*)(eps + (size_t)3 * B * P + (size_t)b0 * P);
    GLOAD_LDS16(ge4 + tid, &sE[tid]);
    if (tid < 64)
        GLOAD_LDS16(ge4 + NTHR + tid, &sE[NTHR + tid]);

    __syncthreads();   // compiler emits s_waitcnt vmcnt(0) lgkmcnt(0) before s_barrier

    const float* sx = (const float*)sX2;
    const float* se = (const float*)sE;

    // Pull the whole x2 row into registers once; reused in epilogue.
    float r2[P * P];
    #pragma unroll
    for (int i = 0; i < P * P; ++i) r2[i] = sx[tid * (P * P) + i];

    float e[P];
    #pragma unroll
    for (int j = 0; j < P; ++j) e[j] = se[tid * P + j];

    // Ce[i] = sum_j x2[i][j] * eps[j]
    float Ce[P];
    #pragma unroll
    for (int i = 0; i < P; ++i) {
        float s = 0.0f;
        #pragma unroll
        for (int j = 0; j < P; ++j) s = fmaf(r2[i * P + j], e[j], s);
        Ce[i] = s;
    }

    float R[P], h[P];
    #pragma unroll
    for (int i = 0; i < P; ++i) { R[i] = MU + Ce[i]; h[i] = R[i]; }

    // 3 bias-free Linear(5,5) + tanh:  h_i = tanh(sum_j h_j * W[l][i][j])
    #pragma unroll
    for (int l = 0; l < 3; ++l) {
        float hn[P];
        #pragma unroll
        for (int i = 0; i < P; ++i) {
            float s = 0.0f;
            #pragma unroll
            for (int j = 0; j < P; ++j) s = fmaf(h[j], sW[l * P * P + i * P + j], s);
            hn[i] = fast_tanh(s);
        }
        #pragma unroll
        for (int i = 0; i < P; ++i) h[i] = hn[i];
    }

    // softmax over P — h in (-1,1) so no max-subtraction needed
    float w[P], ssum = 0.0f;
    #pragma unroll
    for (int i = 0; i < P; ++i) { w[i] = __expf(h[i]); ssum += w[i]; }
    float rs = __builtin_amdgcn_rcpf(ssum);
    #pragma unroll
    for (int i = 0; i < P; ++i) w[i] *= rs;

    // water-filling rebalance; break==freeze (matches reference done semantics)
    float oldv[P], nw[P];
    #pragma unroll
    for (int i = 0; i < P; ++i) {
        oldv[i] = w[i];
        nw[i]   = fminf(fmaxf(w[i], LBV), UBV);
    }
    #pragma unroll
    for (int it = 0; it < 8; ++it) {
        float leftover = 0.0f;
        #pragma unroll
        for (int i = 0; i < P; ++i) leftover += oldv[i] - nw[i];
        float mk[P], msum = 0.0f;
        #pragma unroll
        for (int i = 0; i < P; ++i) {
            mk[i] = (nw[i] != UBV) ? nw[i] : 0.0f;
            msum += mk[i];
        }
        float scale = leftover * __builtin_amdgcn_rcpf(msum);
        float n2[P];
        #pragma unroll
        for (int i = 0; i < P; ++i) n2[i] = fmaf(scale, mk[i], nw[i]);
        bool cont = false;
        #pragma unroll
        for (int i = 0; i < P; ++i) cont = cont || (n2[i] > UBV);
        #pragma unroll
        for (int i = 0; i < P; ++i) {
            oldv[i] = n2[i];
            nw[i]   = cont ? fminf(fmaxf(n2[i], LBV), UBV) : n2[i];
        }
        if (!cont) break;                    // converged rows are frozen from here on
    }

    // wealth = x1 * RF * sum_i nw[i] * (1 + R[i])
    float ws = 0.0f;
    #pragma unroll
    for (int i = 0; i < P; ++i) ws = fmaf(nw[i], 1.0f + R[i], ws);
    out[b0 + tid] = x1v * ws * RFV;

    // curr_cov[i][j] = OMEGA + ALPHA*x2[i][j] + BETA*Ce[j]^2 -> back into LDS row
    float ce2[P];
    #pragma unroll
    for (int j = 0; j < P; ++j) ce2[j] = Ce[j] * Ce[j];
    float* rowo = (float*)sX2 + tid * (P * P);
    #pragma unroll
    for (int i = 0; i < P; ++i) {
        #pragma unroll
        for (int j = 0; j < P; ++j)
            rowo[i * P + j] = fmaf(BETA, ce2[j], fmaf(ALPHA, r2[i * P + j], OMEGA));
    }

    __syncthreads();

    // coalesced dwordx4 cov store (ds_read_b128 + global_store_dwordx4)
    float4* gout4 = (float4*)(out + B + (size_t)b0 * (P * P));
    #pragma unroll
    for (int i = 0; i < 6; ++i)
        gout4[i * NTHR + tid] = sX2[i * NTHR + tid];
    if (tid < 64)
        gout4[6 * NTHR + tid] = sX2[6 * NTHR + tid];
}

extern "C" void kernel_launch(void* const* d_in, const int* in_sizes, int n_in,
                              void* d_out, int out_size, void* d_ws, size_t ws_size,
                              hipStream_t stream) {
    const float* x1  = (const float*)d_in[0];
    const float* x2  = (const float*)d_in[1];
    const float* eps = (const float*)d_in[2];
    const float* W   = (const float*)d_in[3];
    float* out = (float*)d_out;
    const int B = in_sizes[0];           // 524288
    const int blocks = B / NTHR;
    portfolio_kernel<<<blocks, NTHR, 0, stream>>>(x1, x2, eps, W, out, B);
}